// Round 6
// baseline (8099.309 us; speedup 1.0000x reference)
//
#include <hip/hip_runtime.h>
#include <stdint.h>

#define V_ 16000
#define E_ 512
#define H_ 1024
#define B_ 32
#define T_ 64

typedef float f32x4 __attribute__((ext_vector_type(4)));
typedef unsigned long long u64;

__device__ __forceinline__ unsigned int fkey(float f) {
    unsigned int u = __float_as_uint(f);
    return (u & 0x80000000u) ? ~u : (u | 0x80000000u);
}

__global__ void init_kernel(const float* __restrict__ hidden,
                            float* __restrict__ h0, float* __restrict__ h1,
                            u64* __restrict__ tokpk) {
    int idx = blockIdx.x * blockDim.x + threadIdx.x;
    if (idx < B_ * H_) {
        h0[idx] = hidden[idx];
        h1[idx] = hidden[B_ * H_ + idx];
    }
    if (idx < T_ * B_) tokpk[idx] = 0ull;
}

// ---------------------------------------------------------------------------
// GRU fused kernel. Block owns 4 hidden cols i0..i0+3 (grid 256). Streams the
// 12 ih weight rows (3 gates x 4 cols, K=KX) then the 12 hh rows (K=H) through
// LDS with 2-chunk-ahead register prefetch; epilogue does the full GRU combine
// and writes h' directly (no separate combine kernel, no gate buffer).
// Thread org: ks = tid>>6 (4-way K-split); lane: rg = (lane>>4) i-col,
// bgl = lane&15, batch = bgl+16j (j<2). acc[gate][j], gate=vi<3.
// Chunk = 64 k: LDS buf = [W 12x64 | A 32x64] = 2816 floats, x2 buffers.
// f32x4 slots XOR-swizzled by (row&7): all compute reads <=2-way (free).
// Staging: 704 slots (W 192 + A 512), 3 rounds of 256; invalid -> slot 0
// (benign duplicate write of identical data).
// ---------------------------------------------------------------------------
__device__ __forceinline__ void gru_stream(
    const float* const* sp, const int* dofs, int nch,
    float* lds, int tid, float acc[3][2])
{
    const int ks = tid >> 6, lane = tid & 63;
    const int rg = lane >> 4, bgl = lane & 15;

    auto compute = [&](const float* Wb) {
        const float* Ab = Wb + 768;
        #pragma unroll
        for (int kk = 0; kk < 4; kk++) {
            const int k4 = ks * 4 + kk;
            f32x4 wv[3], av[2];
            #pragma unroll
            for (int vi = 0; vi < 3; vi++) {
                const int row = vi * 4 + rg;
                wv[vi] = *(const f32x4*)&Wb[row * 64 + ((k4 ^ (row & 7)) << 2)];
            }
            #pragma unroll
            for (int j = 0; j < 2; j++) {
                const int brow = bgl + 16 * j;
                av[j] = *(const f32x4*)&Ab[brow * 64 + ((k4 ^ (brow & 7)) << 2)];
            }
            #pragma unroll
            for (int vi = 0; vi < 3; vi++)
                #pragma unroll
                for (int j = 0; j < 2; j++)
                    acc[vi][j] += wv[vi].x*av[j].x + wv[vi].y*av[j].y
                                + wv[vi].z*av[j].z + wv[vi].w*av[j].w;
        }
    };

    f32x4 trA[3], trB[3];
    #pragma unroll
    for (int q = 0; q < 3; q++) trA[q] = *(const f32x4*)sp[q];
    #pragma unroll
    for (int q = 0; q < 3; q++) trB[q] = *(const f32x4*)(sp[q] + 64);
    #pragma unroll
    for (int q = 0; q < 3; q++) *(f32x4*)&lds[dofs[q]] = trA[q];
    __syncthreads();

    for (int c = 0; c < nch; c += 2) {
        if (c + 2 < nch) {
            #pragma unroll
            for (int q = 0; q < 3; q++)
                trA[q] = *(const f32x4*)(sp[q] + (c + 2) * 64);
        }
        compute(&lds[0]);                       // chunk c (buf 0)
        #pragma unroll
        for (int q = 0; q < 3; q++) *(f32x4*)&lds[2816 + dofs[q]] = trB[q];
        __syncthreads();
        if (c + 3 < nch) {
            #pragma unroll
            for (int q = 0; q < 3; q++)
                trB[q] = *(const f32x4*)(sp[q] + (c + 3) * 64);
        }
        compute(&lds[2816]);                    // chunk c+1 (buf 1)
        if (c + 2 < nch) {
            #pragma unroll
            for (int q = 0; q < 3; q++) *(f32x4*)&lds[dofs[q]] = trA[q];
        }
        __syncthreads();
    }
}

template<int KX>
__global__ __launch_bounds__(256) void gru_fused(
    const float* __restrict__ Wih, const float* __restrict__ Whh,
    const float* __restrict__ xsrc, const u64* __restrict__ tokprev,
    int t, int tmode,
    const float* __restrict__ hprev,
    const float* __restrict__ bih, const float* __restrict__ bhh,
    float* __restrict__ hnew)
{
    __shared__ float lds[5632];
    const int tid = threadIdx.x;
    const int i0 = blockIdx.x * 4;

    float accI[3][2] = {}, accH[3][2] = {};

    // ---- phase 0: ih (W = Wih, A = x) ----
    {
        const float* sp[3]; int dofs[3];
        #pragma unroll
        for (int q = 0; q < 3; q++) {
            int s = tid + q * 256; if (s >= 704) s = 0;
            if (s < 192) {
                const int row = s >> 4, k4 = s & 15;
                sp[q] = Wih + (size_t)((row >> 2) * H_ + i0 + (row & 3)) * KX + k4 * 4;
                dofs[q] = row * 64 + ((k4 ^ (row & 7)) << 2);
            } else {
                const int sa = s - 192, row = sa >> 4, k4 = sa & 15;
                const float* ab;
                if (tmode) {
                    int tok = 0;
                    if (t > 0)
                        tok = (int)(0xFFFFFFFFu - (unsigned)(tokprev[row] & 0xFFFFFFFFull));
                    ab = xsrc + (size_t)tok * KX;      // xsrc = embed
                } else {
                    ab = xsrc + (size_t)row * KX;      // xsrc = h0' (stride KX==H)
                }
                sp[q] = ab + k4 * 4;
                dofs[q] = 768 + row * 64 + ((k4 ^ (row & 7)) << 2);
            }
        }
        gru_stream(sp, dofs, KX / 64, lds, tid, accI);
    }
    // ---- phase 1: hh (W = Whh, A = hprev) ----
    {
        const float* sp[3]; int dofs[3];
        #pragma unroll
        for (int q = 0; q < 3; q++) {
            int s = tid + q * 256; if (s >= 704) s = 0;
            if (s < 192) {
                const int row = s >> 4, k4 = s & 15;
                sp[q] = Whh + (size_t)((row >> 2) * H_ + i0 + (row & 3)) * H_ + k4 * 4;
                dofs[q] = row * 64 + ((k4 ^ (row & 7)) << 2);
            } else {
                const int sa = s - 192, row = sa >> 4, k4 = sa & 15;
                sp[q] = hprev + (size_t)row * H_ + k4 * 4;
                dofs[q] = 768 + row * 64 + ((k4 ^ (row & 7)) << 2);
            }
        }
        gru_stream(sp, dofs, H_ / 64, lds, tid, accH);
    }

    // ---- reduce across ks + GRU combine ----
    {
        const int ks = tid >> 6, lane = tid & 63;
        float* dst = &lds[(ks * 64 + lane) * 13];
        #pragma unroll
        for (int vi = 0; vi < 3; vi++)
            #pragma unroll
            for (int j = 0; j < 2; j++) {
                dst[vi * 2 + j]     = accI[vi][j];
                dst[6 + vi * 2 + j] = accH[vi][j];
            }
    }
    __syncthreads();
    if (tid < 128) {
        const int il = tid >> 5, b = tid & 31;
        const int bgl = b & 15, j = b >> 4;
        const int lsrc = il * 16 + bgl;
        float sI[3], sH[3];
        #pragma unroll
        for (int vi = 0; vi < 3; vi++) {
            float a = 0.f, h = 0.f;
            #pragma unroll
            for (int k = 0; k < 4; k++) {
                a += lds[(k * 64 + lsrc) * 13 + vi * 2 + j];
                h += lds[(k * 64 + lsrc) * 13 + 6 + vi * 2 + j];
            }
            sI[vi] = a; sH[vi] = h;
        }
        const int ii = i0 + il;
        const float Sr = sI[0] + sH[0] + bih[ii] + bhh[ii];
        const float Sz = sI[1] + sH[1] + bih[H_ + ii] + bhh[H_ + ii];
        const float r = 1.f / (1.f + expf(-Sr));
        const float z = 1.f / (1.f + expf(-Sz));
        const float n = tanhf(sI[2] + bih[2 * H_ + ii] + r * (sH[2] + bhh[2 * H_ + ii]));
        const float hp = hprev[(size_t)b * H_ + ii];
        hnew[(size_t)b * H_ + ii] = (1.f - z) * n + z * hp;
    }
}

// ---------------------------------------------------------------------------
// Logits + fused argmax. 16 vocab rows/block (grid 1000, ~4 blocks/CU).
// Same streamed structure: chunk = 64 k, [W 16x64 | A 32x64] = 3072 floats x2,
// 2-chunk-ahead register prefetch, 768 staging slots = exactly 3/thread.
// Thread tile: rows vg+8vi (vi<2), batch bg+8j (j<4) -> acc[2][4].
// ---------------------------------------------------------------------------
__global__ __launch_bounds__(256) void logits_kernel(
    const float* __restrict__ h1, const float* __restrict__ Wout,
    const float* __restrict__ bout, float* __restrict__ out_t,
    u64* __restrict__ tokpk_t)
{
    __shared__ float lds[6144];
    const int tid = threadIdx.x;
    const int v0 = blockIdx.x * 16;
    const int ks = tid >> 6, lane = tid & 63;
    const int vg = lane >> 3, bg = lane & 7;

    const float* sp[3]; int dofs[3];
    #pragma unroll
    for (int q = 0; q < 3; q++) {
        const int s = tid + q * 256;
        if (s < 256) {
            const int row = s >> 4, k4 = s & 15;
            sp[q] = Wout + (size_t)(v0 + row) * H_ + k4 * 4;
            dofs[q] = row * 64 + ((k4 ^ (row & 7)) << 2);
        } else {
            const int sa = s - 256, row = sa >> 4, k4 = sa & 15;
            sp[q] = h1 + (size_t)row * H_ + k4 * 4;
            dofs[q] = 1024 + row * 64 + ((k4 ^ (row & 7)) << 2);
        }
    }

    float acc[2][4] = {};
    auto compute = [&](const float* Wb) {
        const float* Ab = Wb + 1024;
        #pragma unroll
        for (int kk = 0; kk < 4; kk++) {
            const int k4 = ks * 4 + kk;
            f32x4 wv[2], av[4];
            #pragma unroll
            for (int vi = 0; vi < 2; vi++) {
                const int row = vg + 8 * vi;
                wv[vi] = *(const f32x4*)&Wb[row * 64 + ((k4 ^ (row & 7)) << 2)];
            }
            #pragma unroll
            for (int j = 0; j < 4; j++) {
                const int brow = bg + 8 * j;
                av[j] = *(const f32x4*)&Ab[brow * 64 + ((k4 ^ (brow & 7)) << 2)];
            }
            #pragma unroll
            for (int vi = 0; vi < 2; vi++)
                #pragma unroll
                for (int j = 0; j < 4; j++)
                    acc[vi][j] += wv[vi].x*av[j].x + wv[vi].y*av[j].y
                                + wv[vi].z*av[j].z + wv[vi].w*av[j].w;
        }
    };

    f32x4 trA[3], trB[3];
    #pragma unroll
    for (int q = 0; q < 3; q++) trA[q] = *(const f32x4*)sp[q];
    #pragma unroll
    for (int q = 0; q < 3; q++) trB[q] = *(const f32x4*)(sp[q] + 64);
    #pragma unroll
    for (int q = 0; q < 3; q++) *(f32x4*)&lds[dofs[q]] = trA[q];
    __syncthreads();

    for (int c = 0; c < 16; c += 2) {
        if (c + 2 < 16) {
            #pragma unroll
            for (int q = 0; q < 3; q++)
                trA[q] = *(const f32x4*)(sp[q] + (c + 2) * 64);
        }
        compute(&lds[0]);
        #pragma unroll
        for (int q = 0; q < 3; q++) *(f32x4*)&lds[3072 + dofs[q]] = trB[q];
        __syncthreads();
        if (c + 3 < 16) {
            #pragma unroll
            for (int q = 0; q < 3; q++)
                trB[q] = *(const f32x4*)(sp[q] + (c + 3) * 64);
        }
        compute(&lds[3072]);
        if (c + 2 < 16) {
            #pragma unroll
            for (int q = 0; q < 3; q++) *(f32x4*)&lds[dofs[q]] = trA[q];
        }
        __syncthreads();
    }

    // ---- reduce across ks, bias, store, argmax (LDS overlay) ----
    {
        float* dst = &lds[(ks * 64 + lane) * 9];
        #pragma unroll
        for (int vi = 0; vi < 2; vi++)
            #pragma unroll
            for (int j = 0; j < 4; j++) dst[vi * 4 + j] = acc[vi][j];
    }
    __syncthreads();
    float* totl = lds + 2304;                       // [32][17]
    u64*   am   = (u64*)(lds + 2848);               // [32][8]
    if (tid < 64) {
        const int vgr = tid >> 3, bgr = tid & 7;
        float tv[2][4];
        #pragma unroll
        for (int vi = 0; vi < 2; vi++) {
            const float bo = bout[v0 + vgr + 8 * vi];
            #pragma unroll
            for (int j = 0; j < 4; j++) {
                float s = 0.f;
                #pragma unroll
                for (int k = 0; k < 4; k++)
                    s += lds[(k * 64 + vgr * 8 + bgr) * 9 + vi * 4 + j];
                tv[vi][j] = s + bo;
            }
        }
        #pragma unroll
        for (int vi = 0; vi < 2; vi++)
            #pragma unroll
            for (int j = 0; j < 4; j++)
                totl[(bgr + 8 * j) * 17 + vgr + 8 * vi] = tv[vi][j];
        #pragma unroll
        for (int j = 0; j < 4; j++) {
            u64 best = 0ull;
            #pragma unroll
            for (int vi = 0; vi < 2; vi++) {
                const int v = v0 + vgr + 8 * vi;
                u64 p = ((u64)fkey(tv[vi][j]) << 32)
                      | (u64)(0xFFFFFFFFu - (unsigned)v);
                best = p > best ? p : best;
            }
            am[(bgr + 8 * j) * 8 + vgr] = best;
        }
    }
    __syncthreads();
    if (tid < 64) {
        const int b = tid >> 1, half = tid & 1;
        #pragma unroll
        for (int q = 0; q < 2; q++) {
            f32x4 o;
            o.x = totl[b * 17 + half * 8 + q * 4 + 0];
            o.y = totl[b * 17 + half * 8 + q * 4 + 1];
            o.z = totl[b * 17 + half * 8 + q * 4 + 2];
            o.w = totl[b * 17 + half * 8 + q * 4 + 3];
            __builtin_nontemporal_store(
                o, (f32x4*)(out_t + (size_t)b * V_ + v0 + half * 8 + q * 4));
        }
    }
    if (tid < 32) {
        u64 best = 0ull;
        #pragma unroll
        for (int q = 0; q < 8; q++) {
            u64 p = am[tid * 8 + q];
            best = p > best ? p : best;
        }
        atomicMax(&tokpk_t[tid], best);
    }
}

extern "C" void kernel_launch(void* const* d_in, const int* in_sizes, int n_in,
                              void* d_out, int out_size, void* d_ws, size_t ws_size,
                              hipStream_t stream) {
    const float* hidden = (const float*)d_in[0];
    const float* embed  = (const float*)d_in[1];
    const float* Wih0   = (const float*)d_in[2];
    const float* Whh0   = (const float*)d_in[3];
    const float* bih0   = (const float*)d_in[4];
    const float* bhh0   = (const float*)d_in[5];
    const float* Wih1   = (const float*)d_in[6];
    const float* Whh1   = (const float*)d_in[7];
    const float* bih1   = (const float*)d_in[8];
    const float* bhh1   = (const float*)d_in[9];
    const float* Wout   = (const float*)d_in[10];
    const float* bout   = (const float*)d_in[11];
    float* out = (float*)d_out;

    const int BH = B_ * H_;
    float* ws = (float*)d_ws;
    float* h0buf = ws;                         // [2][B][H]
    float* h1buf = ws + 2 * BH;                // [2][B][H]
    u64* tokpk = (u64*)(ws + 4 * BH);          // [T][B]

    init_kernel<<<128, 256, 0, stream>>>(hidden, h0buf, h1buf, tokpk);

    for (int t = 0; t < T_; t++) {
        const int rp = t & 1, wp = (t + 1) & 1;
        const u64* tokprev = tokpk + (size_t)(t > 0 ? t - 1 : 0) * B_;

        gru_fused<E_><<<H_ / 4, 256, 0, stream>>>(
            Wih0, Whh0, embed, tokprev, t, /*tmode=*/1,
            h0buf + (size_t)rp * BH, bih0, bhh0, h0buf + (size_t)wp * BH);

        gru_fused<H_><<<H_ / 4, 256, 0, stream>>>(
            Wih1, Whh1, h0buf + (size_t)wp * BH, nullptr, 0, /*tmode=*/0,
            h1buf + (size_t)rp * BH, bih1, bhh1, h1buf + (size_t)wp * BH);

        logits_kernel<<<V_ / 16, 256, 0, stream>>>(
            h1buf + (size_t)wp * BH, Wout, bout,
            out + (size_t)t * B_ * V_, tokpk + (size_t)t * B_);
    }
}